// Round 15
// baseline (49.846 us; speedup 1.0000x reference)
//
#include <hip/hip_runtime.h>
#include <hip/hip_bf16.h>

// MyDeConv1D as GEMM: out[b,t,f] = sum_{j,c} x[b,t+28-4j,c]*W[c,j,f] + cnt(t)*256*bias[f]
// M=32768, N=256, K=2048, bf16 MFMA 16x16x32.
// R15: x-stationary register chunks. Per chunk (32 ch): lane loads its 20
//   distinct A granules ONCE (rows l16+4d, d=7-j+4mf covers all taps/frags),
//   then 128 MFMA run pure-register. Staging: pinned-asm f32 global->reg,
//   in-reg cvt, swizzled ds_write (p = g^((row>>1)&3), uniform 8 lanes/quad).
//   Pinned-asm B ring (slot S%3), exact per-wave vmcnt ledger, 1 barrier/chunk.
//   Block 128r x 128f, 4 waves (2m x 2f), 512 blocks = 2/CU. LDS 24.6 KB.

#define B_   16
#define T_   2048
#define C_   256
#define KT   8
#define F_   256
#define SH   28
#define BT   128
#define WIN  156                 // real rows per tile
#define TPAD 192                 // padded rows (uniform 3 staging rounds)
#define TILEB (TPAD * 64)        // 12288 B per bf16 tile buffer

typedef __attribute__((ext_vector_type(8))) short short8;
typedef __attribute__((ext_vector_type(4))) float floatx4;
typedef __attribute__((ext_vector_type(4))) int   intx4;

// Wf frag order (same as R14): fid = S*16 + g, S = c*8 + j. frag (S,g):
// lane(l16,q) holds B[k=q*8+i][f=g*16+l16], c = c*32 + q*8 + i. 1KB/frag.
__global__ __launch_bounds__(256) void wprep_kernel(const float* __restrict__ W,
                                                    ushort* __restrict__ Wf) {
    const int tid  = threadIdx.x;
    const int fid  = blockIdx.x * 4 + (tid >> 6);   // 0..1023
    const int lane = tid & 63;
    const int g    = fid & 15;
    const int S    = fid >> 4;
    const int j    = S & 7, c = S >> 3;
    const int c0   = c * 32 + (lane >> 4) * 8;
    const int f    = g * 16 + (lane & 15);
    short8 pk;
    #pragma unroll
    for (int i = 0; i < 8; ++i) {
        __hip_bfloat16 h = __float2bfloat16(W[((c0 + i) * KT + j) * F_ + f]);
        pk[i] = *reinterpret_cast<const short*>(&h);
    }
    *reinterpret_cast<short8*>(Wf + (size_t)fid * 512 + lane * 8) = pk;
}

__device__ inline short8 cvt8v(floatx4 a, floatx4 b) {
    short8 r;
    #pragma unroll
    for (int i = 0; i < 4; ++i) {
        __hip_bfloat16 h = __float2bfloat16(a[i]);
        r[i] = *reinterpret_cast<const short*>(&h);
    }
    #pragma unroll
    for (int i = 0; i < 4; ++i) {
        __hip_bfloat16 h = __float2bfloat16(b[i]);
        r[i + 4] = *reinterpret_cast<const short*>(&h);
    }
    return r;
}

__global__ __launch_bounds__(256, 2) void deconv_kernel(
        const float* __restrict__ x, const ushort* __restrict__ Wf,
        const float* __restrict__ bias, float* __restrict__ out) {
    __shared__ alignas(16) char smem[2 * TILEB];    // 24576 B
    const int bid = blockIdx.x;                 // (tt*16 + b)*2 + fh
    const int fh  = bid & 1;
    const int tb  = bid >> 1;
    const int b   = tb & 15;
    const int t0  = (tb >> 4) * BT;
    const int tid = threadIdx.x;
    const int w   = tid >> 6, lane = tid & 63;
    const int l16 = lane & 15, q = lane >> 4;
    const int wm  = w >> 1, wf2 = w & 1;
    const char* wfbase = (const char*)Wf +
        (size_t)(fh * 8 + wf2 * 4) * 1024 + (size_t)lane * 16;
    // staging geometry: thread handles tasks (row = tid>>2 + 64k, g = tid&3)
    const int srow = tid >> 2, sg = tid & 3;

#define VMW(N_) do { asm volatile("s_waitcnt vmcnt(" #N_ ")" ::: "memory"); \
        __builtin_amdgcn_sched_barrier(0); } while (0)
#define LKW() do { asm volatile("s_waitcnt lgkmcnt(0)" ::: "memory");       \
        __builtin_amdgcn_sched_barrier(0); } while (0)
#define BAR() do { __builtin_amdgcn_sched_barrier(0);                       \
        __builtin_amdgcn_s_barrier();                                       \
        asm volatile("" ::: "memory");                                      \
        __builtin_amdgcn_sched_barrier(0); } while (0)

    // pinned stage loads: 6 per thread per chunk (uniform across waves)
#define SL_ISSUE(cs_) do {                                                  \
        _Pragma("unroll")                                                   \
        for (int k = 0; k < 3; ++k) {                                       \
            int tr_ = t0 + srow + 64 * k;                                   \
            if (tr_ > T_ - 1) tr_ = T_ - 1;                                 \
            const char* p_ = (const char*)(x +                              \
                ((size_t)(b * T_ + tr_) * C_ + (cs_) * 32 + sg * 8));       \
            asm volatile("global_load_dwordx4 %0, %1, off"                  \
                : "=v"(sl[k][0]) : "v"(p_) : "memory");                     \
            asm volatile("global_load_dwordx4 %0, %1, off offset:16"        \
                : "=v"(sl[k][1]) : "v"(p_) : "memory");                     \
        } } while (0)

    // convert + swizzled ds_write of staged rows into tile buf_
#define CVT_WRITE(buf_) do {                                                \
        _Pragma("unroll")                                                   \
        for (int k = 0; k < 3; ++k) {                                       \
            const int row_ = srow + 64 * k;                                 \
            short8 pk_ = {0,0,0,0,0,0,0,0};                                 \
            if (t0 + row_ < T_) pk_ = cvt8v(sl[k][0], sl[k][1]);            \
            const int p_ = sg ^ ((row_ >> 1) & 3);                          \
            *(short8*)(smem + (buf_) * TILEB + row_ * 64 + p_ * 16) = pk_;  \
        } } while (0)

    // per-lane A granules for the whole chunk: rows wm*64 + l16 + 4d
#define A_LOAD(buf_) do {                                                   \
        _Pragma("unroll")                                                   \
        for (int d = 0; d < 20; ++d) {                                      \
            const int row_ = wm * 64 + l16 + 4 * d;                         \
            const int p_   = q ^ ((row_ >> 1) & 3);                         \
            a[d] = *(const short8*)(smem + (buf_) * TILEB +                 \
                                    row_ * 64 + p_ * 16);                   \
        } } while (0)

#define B_ISSUE(S_, sl_) do {                                               \
        const char* p_ = wfbase + (size_t)(S_) * 16384;                     \
        asm volatile("global_load_dwordx4 %0, %1, off"                      \
            : "=v"(bR[sl_][0]) : "v"(p_) : "memory");                       \
        asm volatile("global_load_dwordx4 %0, %1, off offset:1024"          \
            : "=v"(bR[sl_][1]) : "v"(p_) : "memory");                       \
        asm volatile("global_load_dwordx4 %0, %1, off offset:2048"          \
            : "=v"(bR[sl_][2]) : "v"(p_) : "memory");                       \
        asm volatile("global_load_dwordx4 %0, %1, off offset:3072"          \
            : "=v"(bR[sl_][3]) : "v"(p_) : "memory");                       \
        } while (0)

    // tap j: A from registers a[7-j+4mf], B from ring slot
#define MFMA_TAP(j_, slot_) do {                                            \
        __builtin_amdgcn_s_setprio(1);                                      \
        _Pragma("unroll")                                                   \
        for (int mf = 0; mf < 4; ++mf)                                      \
            _Pragma("unroll")                                               \
            for (int nf = 0; nf < 4; ++nf)                                  \
                acc[mf][nf] = __builtin_amdgcn_mfma_f32_16x16x32_bf16(      \
                    a[7 - (j_) + 4 * mf],                                   \
                    *(short8*)&bR[slot_][nf],                               \
                    acc[mf][nf], 0, 0, 0);                                  \
        __builtin_amdgcn_s_setprio(0);                                      \
        } while (0)

#define CHUNK(c_) do {                                                      \
        A_LOAD((c_) & 1);                                                   \
        B_ISSUE((c_)*8+2, (((c_)*8+2)%3)); VMW(8);                          \
        MFMA_TAP(0, (((c_)*8+0)%3));                                        \
        B_ISSUE((c_)*8+3, (((c_)*8+3)%3)); VMW(8);                          \
        MFMA_TAP(1, (((c_)*8+1)%3));                                        \
        SL_ISSUE((c_) + 1);                                                 \
        B_ISSUE((c_)*8+4, (((c_)*8+4)%3)); VMW(14);                         \
        MFMA_TAP(2, (((c_)*8+2)%3));                                        \
        B_ISSUE((c_)*8+5, (((c_)*8+5)%3)); VMW(14);                         \
        MFMA_TAP(3, (((c_)*8+3)%3));                                        \
        B_ISSUE((c_)*8+6, (((c_)*8+6)%3)); VMW(8);                          \
        MFMA_TAP(4, (((c_)*8+4)%3));                                        \
        B_ISSUE((c_)*8+7, (((c_)*8+7)%3)); VMW(8);                          \
        MFMA_TAP(5, (((c_)*8+5)%3));                                        \
        CVT_WRITE(((c_) + 1) & 1);                                          \
        B_ISSUE((c_)*8+8, (((c_)*8+8)%3)); VMW(8);                          \
        MFMA_TAP(6, (((c_)*8+6)%3));                                        \
        B_ISSUE((c_)*8+9, (((c_)*8+9)%3)); VMW(8);                          \
        MFMA_TAP(7, (((c_)*8+7)%3));                                        \
        LKW(); BAR();                                                       \
        } while (0)

    float bf4[4];
    #pragma unroll
    for (int nf = 0; nf < 4; ++nf)
        bf4[nf] = bias[fh * 128 + wf2 * 64 + nf * 16 + l16];

    floatx4 acc[4][4];
    #pragma unroll
    for (int mf = 0; mf < 4; ++mf)
        #pragma unroll
        for (int nf = 0; nf < 4; ++nf)
            acc[mf][nf] = (floatx4){0.f, 0.f, 0.f, 0.f};

    short8  a[20];                // per-lane A granules (80 VGPR)
    intx4   bR[3][4];             // B ring (48 VGPR)
    floatx4 sl[3][2];             // staging regs (24 VGPR)

    // ---- prologue: stage tile 0, prime B(0),B(1) ----
    SL_ISSUE(0);
    B_ISSUE(0, 0); B_ISSUE(1, 1);
    VMW(8);                       // retire the 6 SL loads; B(0),B(1) in flight
    CVT_WRITE(0);
    LKW(); BAR();

    CHUNK(0); CHUNK(1); CHUNK(2); CHUNK(3);
    CHUNK(4); CHUNK(5); CHUNK(6);

    // ---- last chunk (c=7): no SL, no CVT ----
    A_LOAD(1);
    B_ISSUE(58, 1); VMW(8); MFMA_TAP(0, 2);
    B_ISSUE(59, 2); VMW(8); MFMA_TAP(1, 0);
    B_ISSUE(60, 0); VMW(8); MFMA_TAP(2, 1);
    B_ISSUE(61, 1); VMW(8); MFMA_TAP(3, 2);
    B_ISSUE(62, 2); VMW(8); MFMA_TAP(4, 0);
    B_ISSUE(63, 0); VMW(8); MFMA_TAP(5, 1);
    VMW(4); MFMA_TAP(6, 2);
    VMW(0); MFMA_TAP(7, 0);

    // ---- epilogue: + cnt(t)*256*bias; C/D map col=l16 (f), row=q*4+r ----
    #pragma unroll
    for (int mf = 0; mf < 4; ++mf) {
        #pragma unroll
        for (int nf = 0; nf < 4; ++nf) {
            const int f = fh * 128 + wf2 * 64 + nf * 16 + l16;
            #pragma unroll
            for (int r = 0; r < 4; ++r) {
                const int t = t0 + wm * 64 + mf * 16 + q * 4 + r;
                const int jmin = (t < T_ - SH) ? 0 : (((t - (T_ - SH)) >> 2) + 1);
                out[(size_t)(b * T_ + t) * F_ + f] =
                    acc[mf][nf][r] + (float)(8 - jmin) * 256.0f * bf4[nf];
            }
        }
    }
#undef VMW
#undef LKW
#undef BAR
#undef SL_ISSUE
#undef CVT_WRITE
#undef A_LOAD
#undef B_ISSUE
#undef MFMA_TAP
#undef CHUNK
}

extern "C" void kernel_launch(void* const* d_in, const int* in_sizes, int n_in,
                              void* d_out, int out_size, void* d_ws, size_t ws_size,
                              hipStream_t stream) {
    const float* x    = (const float*)d_in[0];
    const float* W    = (const float*)d_in[1];   // (C,KT,F)
    const float* bias = (const float*)d_in[2];
    float* out = (float*)d_out;
    ushort* Wf = (ushort*)d_ws;                  // 1 MiB scratch

    wprep_kernel<<<256, 256, 0, stream>>>(W, Wf);
    deconv_kernel<<<512, 256, 0, stream>>>(x, Wf, bias, out);
}

// Round 16
// 43.889 us; speedup vs baseline: 1.1357x; 1.1357x over previous
//
#include <hip/hip_runtime.h>
#include <hip/hip_bf16.h>

// MyDeConv1D as GEMM: out[b,t,f] = sum_{j,c} x[b,t+28-4j,c]*W[c,j,f] + cnt(t)*256*bias[f]
// M=32768, N=256, K=2048, bf16 MFMA 16x16x32.
// R16 = R14 + source-order A-ring (tap j+2's ds_reads issued right after tap
//   j's MFMA, one sched-region early -> compiler emits counted lgkmcnt and
//   hides LDS latency under MFMA) + single f32 staging buffer (LDS 39.9 KB).
//   Pinned-asm B ring (slot S%3) + exact per-wave vmcnt ledger unchanged.
//   Block 128r x 128f, 4 waves (2m x 2f), 512 blocks = 2/CU.

#define B_   16
#define T_   2048
#define C_   256
#define KT   8
#define F_   256
#define SH   28
#define BT   128
#define WIN  156                 // rows per tile
#define FB   19968               // f32 staging buf bytes (156*8 granules * 16B)
#define ABF  19968               // bf16 tiles base offset
#define ABFB 9984                // bytes per bf16 tile (156*4 granules * 16B)
// total LDS = FB + 2*ABFB = 39936 B

typedef __attribute__((ext_vector_type(8))) short short8;
typedef __attribute__((ext_vector_type(4))) float floatx4;
typedef __attribute__((ext_vector_type(4))) int   intx4;

__device__ inline void gload16(const void* g, void* l) {
    __builtin_amdgcn_global_load_lds(
        (const __attribute__((address_space(1))) void*)g,
        (__attribute__((address_space(3))) void*)l, 16, 0, 0);
}

__device__ inline short8 cvt8(float4 a, float4 b) {
    float v[8] = {a.x, a.y, a.z, a.w, b.x, b.y, b.z, b.w};
    short8 r;
    #pragma unroll
    for (int i = 0; i < 8; ++i) {
        __hip_bfloat16 h = __float2bfloat16(v[i]);
        r[i] = *reinterpret_cast<const short*>(&h);
    }
    return r;
}

// Wf frag order: fid = S*16 + g, S = c*8 + j. frag (S,g): lane(l16,q) holds
// B[k=q*8+i][f=g*16+l16], c = c*32 + q*8 + i. 1KB/frag coalesced.
__global__ __launch_bounds__(256) void wprep_kernel(const float* __restrict__ W,
                                                    ushort* __restrict__ Wf) {
    const int tid  = threadIdx.x;
    const int fid  = blockIdx.x * 4 + (tid >> 6);   // 0..1023
    const int lane = tid & 63;
    const int g    = fid & 15;
    const int S    = fid >> 4;
    const int j    = S & 7, c = S >> 3;
    const int c0   = c * 32 + (lane >> 4) * 8;
    const int f    = g * 16 + (lane & 15);
    short8 pk;
    #pragma unroll
    for (int i = 0; i < 8; ++i) {
        __hip_bfloat16 h = __float2bfloat16(W[((c0 + i) * KT + j) * F_ + f]);
        pk[i] = *reinterpret_cast<const short*>(&h);
    }
    *reinterpret_cast<short8*>(Wf + (size_t)fid * 512 + lane * 8) = pk;
}

__global__ __launch_bounds__(256, 2) void deconv_kernel(
        const float* __restrict__ x, const ushort* __restrict__ Wf,
        const float* __restrict__ bias, float* __restrict__ out) {
    __shared__ alignas(16) char smem[39936];
    const int bid = blockIdx.x;                 // (tt*16 + b)*2 + fh
    const int fh  = bid & 1;
    const int tb  = bid >> 1;
    const int b   = tb & 15;
    const int t0  = (tb >> 4) * BT;
    const int tid = threadIdx.x;
    const int w   = tid >> 6, lane = tid & 63;
    const int l16 = lane & 15, q = lane >> 4;
    const int wm  = w >> 1, wf2 = w & 1;
    const char* wfbase = (const char*)Wf +
        (size_t)(fh * 8 + wf2 * 4) * 1024 + (size_t)lane * 16;

#define VMW(N_) do { asm volatile("s_waitcnt vmcnt(" #N_ ")" ::: "memory"); \
        __builtin_amdgcn_sched_barrier(0); } while (0)
#define LKW() do { asm volatile("s_waitcnt lgkmcnt(0)" ::: "memory");       \
        __builtin_amdgcn_sched_barrier(0); } while (0)
#define BAR() do { __builtin_amdgcn_sched_barrier(0);                       \
        __builtin_amdgcn_s_barrier();                                       \
        asm volatile("" ::: "memory");                                      \
        __builtin_amdgcn_sched_barrier(0); } while (0)

    // A stage round k for chunk cc -> single f32 buf. Linear dest (granule u);
    // source granule v = (s - row) mod 8 so CVT reads are bank-uniform.
#define A_ROUND(k_, cc_) do {                                               \
        const int u_ = (k_) * 256 + tid;                                    \
        if ((k_) < 4 || tid < 224) {                                        \
            const int row_ = u_ >> 3, s_ = u_ & 7;                          \
            const int v_   = (s_ + 8 - (row_ & 7)) & 7;                     \
            int tr_ = t0 + row_; if (tr_ > T_ - 1) tr_ = T_ - 1;            \
            gload16(x + ((size_t)(b * T_ + tr_) * C_ + (cc_) * 32 + v_ * 4),\
                    smem + ((k_) * 256 + w * 64) * 16);                     \
        } } while (0)

    // pinned B frag loads (flat 64b vaddr), tile S -> ring slot sl
#define B_ISSUE(S_, sl_) do {                                               \
        const char* p_ = wfbase + (size_t)(S_) * 16384;                     \
        asm volatile("global_load_dwordx4 %0, %1, off"                      \
            : "=v"(bR[sl_][0]) : "v"(p_) : "memory");                       \
        asm volatile("global_load_dwordx4 %0, %1, off offset:1024"          \
            : "=v"(bR[sl_][1]) : "v"(p_) : "memory");                       \
        asm volatile("global_load_dwordx4 %0, %1, off offset:2048"          \
            : "=v"(bR[sl_][2]) : "v"(p_) : "memory");                       \
        asm volatile("global_load_dwordx4 %0, %1, off offset:3072"          \
            : "=v"(bR[sl_][3]) : "v"(p_) : "memory");                       \
        } while (0)

    // f32 -> bf16 convert round r, dest tile parity par
#define CVT_ROUND(r_, par_) do {                                            \
        if ((r_) < 2 || tid < 112) {                                        \
            const int task_ = (r_) * 256 + tid;                             \
            const int row_ = task_ >> 2, g_ = task_ & 3;                    \
            const int s1_ = (2 * g_ + row_) & 7;                            \
            const int s2_ = (2 * g_ + 1 + row_) & 7;                        \
            float4 u0_ = *(const float4*)(smem + (row_ * 8 + s1_) * 16);    \
            float4 u1_ = *(const float4*)(smem + (row_ * 8 + s2_) * 16);    \
            short8 pk_ = {0,0,0,0,0,0,0,0};                                 \
            if (t0 + row_ < T_) pk_ = cvt8(u0_, u1_);                       \
            const int p_ = g_ ^ ((row_ >> 1) & 3);                          \
            *(short8*)(smem + ABF + (par_) * ABFB + (row_ * 4 + p_) * 16)   \
                = pk_;                                                      \
        } } while (0)

    // A frags for tap j from tile buf_ -> ring arr (C-level: compiler pipelines)
#define LOAD_A(buf_, j_, arr) do {                                          \
        const char* ab_ = smem + ABF + (buf_) * ABFB;                       \
        _Pragma("unroll")                                                   \
        for (int mf = 0; mf < 4; ++mf) {                                    \
            const int row_ = wm * 64 + (SH - 4 * (j_)) + mf * 16 + l16;     \
            const int p_   = q ^ ((row_ >> 1) & 3);                         \
            arr[mf] = *(const short8*)(ab_ + (row_ * 4 + p_) * 16);         \
        } } while (0)

#define MFMA_TAP(arr, slot_) do {                                           \
        __builtin_amdgcn_s_setprio(1);                                      \
        _Pragma("unroll")                                                   \
        for (int mf = 0; mf < 4; ++mf)                                      \
            _Pragma("unroll")                                               \
            for (int nf = 0; nf < 4; ++nf)                                  \
                acc[mf][nf] = __builtin_amdgcn_mfma_f32_16x16x32_bf16(      \
                    arr[mf], *(short8*)&bR[slot_][nf],                      \
                    acc[mf][nf], 0, 0, 0);                                  \
        __builtin_amdgcn_s_setprio(0);                                      \
        } while (0)

#define CHUNK(c_) do {                                                      \
        LOAD_A((c_) & 1, 0, a0);                                            \
        A_ROUND(0, (c_)+1); A_ROUND(1, (c_)+1); A_ROUND(2, (c_)+1);         \
        A_ROUND(3, (c_)+1); A_ROUND(4, (c_)+1);                             \
        LOAD_A((c_) & 1, 1, a1);                                            \
        B_ISSUE((c_)*8+2, (((c_)*8+2)%3)); VMW(13);                         \
        MFMA_TAP(a0, (((c_)*8+0)%3));                                       \
        LOAD_A((c_) & 1, 2, a0);                                            \
        B_ISSUE((c_)*8+3, (((c_)*8+3)%3)); VMW(13);                         \
        MFMA_TAP(a1, (((c_)*8+1)%3));                                       \
        LOAD_A((c_) & 1, 3, a1);                                            \
        B_ISSUE((c_)*8+4, (((c_)*8+4)%3)); VMW(8);                          \
        MFMA_TAP(a0, (((c_)*8+2)%3));                                       \
        BAR();                                                              \
        LOAD_A((c_) & 1, 4, a0);                                            \
        B_ISSUE((c_)*8+5, (((c_)*8+5)%3)); VMW(8);                          \
        MFMA_TAP(a1, (((c_)*8+3)%3));                                       \
        LOAD_A((c_) & 1, 5, a1);                                            \
        CVT_ROUND(0, ((c_)+1)&1);                                           \
        B_ISSUE((c_)*8+6, (((c_)*8+6)%3)); VMW(8);                          \
        MFMA_TAP(a0, (((c_)*8+4)%3));                                       \
        LOAD_A((c_) & 1, 6, a0);                                            \
        CVT_ROUND(1, ((c_)+1)&1);                                           \
        B_ISSUE((c_)*8+7, (((c_)*8+7)%3)); VMW(8);                          \
        MFMA_TAP(a1, (((c_)*8+5)%3));                                       \
        LOAD_A((c_) & 1, 7, a1);                                            \
        CVT_ROUND(2, ((c_)+1)&1);                                           \
        B_ISSUE((c_)*8+8, (((c_)*8+8)%3)); VMW(8);                          \
        MFMA_TAP(a0, (((c_)*8+6)%3));                                       \
        B_ISSUE((c_)*8+9, (((c_)*8+9)%3)); VMW(8);                          \
        MFMA_TAP(a1, (((c_)*8+7)%3));                                       \
        LKW(); BAR();                                                       \
        } while (0)

    float bf4[4];
    #pragma unroll
    for (int nf = 0; nf < 4; ++nf)
        bf4[nf] = bias[fh * 128 + wf2 * 64 + nf * 16 + l16];

    floatx4 acc[4][4];
    #pragma unroll
    for (int mf = 0; mf < 4; ++mf)
        #pragma unroll
        for (int nf = 0; nf < 4; ++nf)
            acc[mf][nf] = (floatx4){0.f, 0.f, 0.f, 0.f};

    short8 a0[4], a1[4];          // depth-2 A ring (32 VGPR)
    intx4  bR[3][4];              // pinned B ring (48 VGPR)

    // ---- prologue: stage chunk 0, prime B(0),B(1), convert tile 0 ----
    A_ROUND(0, 0); A_ROUND(1, 0); A_ROUND(2, 0); A_ROUND(3, 0); A_ROUND(4, 0);
    B_ISSUE(0, 0); B_ISSUE(1, 1);
    VMW(8);                        // retire the 5 A gloads; B(0),B(1) in flight
    BAR();
    CVT_ROUND(0, 0); CVT_ROUND(1, 0); CVT_ROUND(2, 0);
    LKW(); BAR();

    CHUNK(0); CHUNK(1); CHUNK(2); CHUNK(3);
    CHUNK(4); CHUNK(5); CHUNK(6);

    // ---- last chunk (c=7): no staging, no CVT ----
    LOAD_A(1, 0, a0);
    LOAD_A(1, 1, a1);
    B_ISSUE(58, 1); VMW(8); MFMA_TAP(a0, 2); LOAD_A(1, 2, a0);
    B_ISSUE(59, 2); VMW(8); MFMA_TAP(a1, 0); LOAD_A(1, 3, a1);
    B_ISSUE(60, 0); VMW(8); MFMA_TAP(a0, 1); LOAD_A(1, 4, a0);
    B_ISSUE(61, 1); VMW(8); MFMA_TAP(a1, 2); LOAD_A(1, 5, a1);
    B_ISSUE(62, 2); VMW(8); MFMA_TAP(a0, 0); LOAD_A(1, 6, a0);
    B_ISSUE(63, 0); VMW(8); MFMA_TAP(a1, 1); LOAD_A(1, 7, a1);
    VMW(4); MFMA_TAP(a0, 2);
    VMW(0); MFMA_TAP(a1, 0);

    // ---- epilogue: + cnt(t)*256*bias; C/D map col=l16 (f), row=q*4+r ----
    #pragma unroll
    for (int mf = 0; mf < 4; ++mf) {
        #pragma unroll
        for (int nf = 0; nf < 4; ++nf) {
            const int f = fh * 128 + wf2 * 64 + nf * 16 + l16;
            #pragma unroll
            for (int r = 0; r < 4; ++r) {
                const int t = t0 + wm * 64 + mf * 16 + q * 4 + r;
                const int jmin = (t < T_ - SH) ? 0 : (((t - (T_ - SH)) >> 2) + 1);
                out[(size_t)(b * T_ + t) * F_ + f] =
                    acc[mf][nf][r] + (float)(8 - jmin) * 256.0f * bf4[nf];
            }
        }
    }
#undef VMW
#undef LKW
#undef BAR
#undef A_ROUND
#undef B_ISSUE
#undef CVT_ROUND
#undef LOAD_A
#undef MFMA_TAP
#undef CHUNK
}

extern "C" void kernel_launch(void* const* d_in, const int* in_sizes, int n_in,
                              void* d_out, int out_size, void* d_ws, size_t ws_size,
                              hipStream_t stream) {
    const float* x    = (const float*)d_in[0];
    const float* W    = (const float*)d_in[1];   // (C,KT,F)
    const float* bias = (const float*)d_in[2];
    float* out = (float*)d_out;
    ushort* Wf = (ushort*)d_ws;                  // 1 MiB scratch

    wprep_kernel<<<256, 256, 0, stream>>>(W, Wf);
    deconv_kernel<<<512, 256, 0, stream>>>(x, Wf, bias, out);
}